// Round 1
// baseline (974.101 us; speedup 1.0000x reference)
//
#include <hip/hip_runtime.h>

#define N_NODES 200000
#define N_EDGES 1000000
#define NG      512
#define D_NODE  128
#define D_EDGE  64
#define HDIM    256

typedef __attribute__((ext_vector_type(8))) short  short8;   // 8 bf16 in 4 VGPRs
typedef __attribute__((ext_vector_type(4))) float  f32x4;

__device__ __forceinline__ unsigned short f2bf(float f) {
    unsigned u = __float_as_uint(f);
    u += 0x7FFFu + ((u >> 16) & 1u);      // RNE
    return (unsigned short)(u >> 16);
}
__device__ __forceinline__ unsigned pack2(float a, float b) {
    return (unsigned)f2bf(a) | ((unsigned)f2bf(b) << 16);
}

// ---------------- histogram / sort kernels ----------------

__global__ __launch_bounds__(256) void node_hist_kernel(
    const int* __restrict__ batch_idx, int* __restrict__ node_cnt)
{
    __shared__ int h[NG];
    for (int i = threadIdx.x; i < NG; i += 256) h[i] = 0;
    __syncthreads();
    for (int n = blockIdx.x * 256 + threadIdx.x; n < N_NODES; n += gridDim.x * 256)
        atomicAdd(&h[batch_idx[n]], 1);
    __syncthreads();
    for (int i = threadIdx.x; i < NG; i += 256)
        if (h[i]) atomicAdd(&node_cnt[i], h[i]);
}

__global__ __launch_bounds__(256) void edge_hist_kernel(
    const int* __restrict__ edge_src, const int* __restrict__ batch_idx,
    int* __restrict__ edge_batch, int* __restrict__ edge_cnt)
{
    __shared__ int h[NG];
    for (int i = threadIdx.x; i < NG; i += 256) h[i] = 0;
    __syncthreads();
    for (int e = blockIdx.x * 256 + threadIdx.x; e < N_EDGES; e += gridDim.x * 256) {
        int g = batch_idx[edge_src[e]];
        edge_batch[e] = g;
        atomicAdd(&h[g], 1);
    }
    __syncthreads();
    for (int i = threadIdx.x; i < NG; i += 256)
        if (h[i]) atomicAdd(&edge_cnt[i], h[i]);
}

__global__ __launch_bounds__(512) void scan_kernel(
    const int* __restrict__ edge_cnt, int* __restrict__ edge_base,
    int* __restrict__ edge_cursor)
{
    __shared__ int tmp[NG];
    int i = threadIdx.x;               // 512 threads
    int v = edge_cnt[i];
    tmp[i] = v;
    __syncthreads();
    int sum = v;
    for (int off = 1; off < NG; off <<= 1) {
        int add = (i >= off) ? tmp[i - off] : 0;
        __syncthreads();
        sum += add;
        tmp[i] = sum;
        __syncthreads();
    }
    int excl = sum - v;
    edge_base[i]   = excl;
    edge_cursor[i] = excl;
}

__global__ __launch_bounds__(256) void scatter_kernel(
    const int* __restrict__ edge_batch, int* __restrict__ edge_cursor,
    int* __restrict__ sorted_edge, int* __restrict__ sorted_seg)
{
    for (int e = blockIdx.x * 256 + threadIdx.x; e < N_EDGES; e += gridDim.x * 256) {
        int g = edge_batch[e];
        int pos = atomicAdd(&edge_cursor[g], 1);
        sorted_edge[pos] = e;
        sorted_seg[pos]  = g;
    }
}

// ---------------- fused GEMM1 + relu + segment-sum ----------------
// Computes hsum[g][:] += sum over rows r with seg(r)==g of relu(X[r]@W + bias)
// Tile: 64 rows x 256 cols, 4 waves (one per 64-col group), 16x16x32 bf16 MFMA.

template<int K, bool GATHER>
__global__ __launch_bounds__(256, 2) void gemm_seg_kernel(
    const float* __restrict__ X,      // rows of length K (f32)
    const float* __restrict__ W,      // [K][256] f32
    const float* __restrict__ bias,   // [256]
    const int*  __restrict__ rowidx,  // GATHER: sorted row indices, else unused
    const int*  __restrict__ segids,  // per (sorted) row: graph id
    float* __restrict__ hsum,         // [512][256] f32, atomically accumulated
    int ntiles)
{
    constexpr int ROWB = K * 2;       // LDS bytes per row (bf16)
    constexpr int KS   = K / 32;      // MFMA k-steps
    __shared__ __align__(16) char smem[64 * ROWB];
    __shared__ int seg_lds[64];
    __shared__ int row_lds[GATHER ? 64 : 1];

    const int tid  = threadIdx.x;
    const int lane = tid & 63;
    const int wv   = tid >> 6;        // wave 0..3 -> col group
    const int hi   = lane >> 4;       // 0..3
    const int lo   = lane & 15;
    const int colbase = wv * 64;

    // --- B fragments in registers (whole W column-slab for this wave) ---
    short8 bfrag[4][KS];
#pragma unroll
    for (int ct = 0; ct < 4; ++ct) {
        const int col = colbase + ct * 16 + lo;
#pragma unroll
        for (int ks = 0; ks < KS; ++ks) {
            short8 f;
#pragma unroll
            for (int j = 0; j < 8; ++j) {
                int k = ks * 32 + hi * 8 + j;
                f[j] = (short)f2bf(W[k * HDIM + col]);
            }
            bfrag[ct][ks] = f;
        }
    }
    float biasv[4];
#pragma unroll
    for (int ct = 0; ct < 4; ++ct) biasv[ct] = bias[colbase + ct * 16 + lo];

    for (int tile = blockIdx.x; tile < ntiles; tile += gridDim.x) {
        // stage ids
        if (tid < 64) {
            int r = tile * 64 + tid;
            seg_lds[tid] = segids[r];
            if (GATHER) row_lds[tid] = rowidx[r];
        }
        __syncthreads();

        // stage X tile -> LDS (bf16, XOR-swizzled 16B chunks)
        constexpr int F4_PER_ROW = K / 4;
        constexpr int NJ = (64 * F4_PER_ROW) / 256;
#pragma unroll
        for (int j = 0; j < NJ; ++j) {
            int f4  = tid + j * 256;
            int row = f4 / F4_PER_ROW;
            int c4  = f4 % F4_PER_ROW;
            float4 v;
            if (GATHER) {
                size_t sr = (size_t)row_lds[row];
                v = *(const float4*)(X + sr * K + c4 * 4);
            } else {
                v = *(const float4*)(X + (size_t)tile * 64 * K + (size_t)f4 * 4);
            }
            int2 p;
            p.x = (int)pack2(v.x, v.y);
            p.y = (int)pack2(v.z, v.w);
            int dst = row * ROWB + ((c4 * 8) ^ ((row & 7) << 4));
            *(int2*)(smem + dst) = p;
        }
        __syncthreads();

        // MFMA: acc[rt][ct] = X[rt*16.., :] @ W[:, ct*16..]
        f32x4 acc[4][4];
#pragma unroll
        for (int rt = 0; rt < 4; ++rt)
#pragma unroll
            for (int ct = 0; ct < 4; ++ct) acc[rt][ct] = f32x4{0.f, 0.f, 0.f, 0.f};

#pragma unroll
        for (int ks = 0; ks < KS; ++ks) {
            short8 a[4];
#pragma unroll
            for (int rt = 0; rt < 4; ++rt) {
                int row  = rt * 16 + lo;
                int koff = ks * 64 + hi * 16;
                a[rt] = *(const short8*)(smem + row * ROWB + (koff ^ ((row & 7) << 4)));
            }
#pragma unroll
            for (int rt = 0; rt < 4; ++rt)
#pragma unroll
                for (int ct = 0; ct < 4; ++ct)
                    acc[rt][ct] = __builtin_amdgcn_mfma_f32_16x16x32_bf16(
                        a[rt], bfrag[ct][ks], acc[rt][ct], 0, 0, 0);
        }

        // bias + relu in-place
#pragma unroll
        for (int rt = 0; rt < 4; ++rt)
#pragma unroll
            for (int ct = 0; ct < 4; ++ct)
#pragma unroll
                for (int r = 0; r < 4; ++r) {
                    float v = acc[rt][ct][r] + biasv[ct];
                    acc[rt][ct][r] = v > 0.f ? v : 0.f;
                }

        // segment accumulate over contiguous runs of equal graph id
        int start = 0;
        while (start < 64) {
            int g   = seg_lds[start];
            int end = start + 1;
            while (end < 64 && seg_lds[end] == g) ++end;
#pragma unroll
            for (int ct = 0; ct < 4; ++ct) {
                float s = 0.f;
#pragma unroll
                for (int rt = 0; rt < 4; ++rt) {
                    int rbase = rt * 16 + hi * 4;
#pragma unroll
                    for (int r = 0; r < 4; ++r) {
                        int row = rbase + r;
                        if (row >= start && row < end) s += acc[rt][ct][r];
                    }
                }
                s += __shfl_xor(s, 16);
                s += __shfl_xor(s, 32);
                if (lane < 16)
                    atomicAdd(&hsum[g * HDIM + colbase + ct * 16 + lane], s);
            }
            start = end;
        }
        __syncthreads();   // protect smem/seg_lds before next tile
    }
}

// ---------------- finisher: means, 2nd linears, combine ----------------
// out[g] = (nr + er) @ Wc + bc, nr = cnt_n>0 ? mean_hn@Wn2+bn2 : 0, similarly er.

__global__ __launch_bounds__(256) void final_kernel(
    const float* __restrict__ node_hsum, const float* __restrict__ edge_hsum,
    const int* __restrict__ node_cnt, const int* __restrict__ edge_cnt,
    const float* __restrict__ Wn2, const float* __restrict__ bn2,
    const float* __restrict__ We2, const float* __restrict__ be2,
    const float* __restrict__ Wc,  const float* __restrict__ bc,
    float* __restrict__ out)
{
    __shared__ float mn[8][HDIM], me[8][HDIM], tt[8][HDIM];
    __shared__ int cf[8], ef[8];
    const int j = threadIdx.x;

#pragma unroll
    for (int gg = 0; gg < 8; ++gg) {
        int g = blockIdx.x * 8 + gg;
        int cn = node_cnt[g], ce = edge_cnt[g];
        if (j == 0) { cf[gg] = cn; ef[gg] = ce; }
        mn[gg][j] = cn > 0 ? node_hsum[g * HDIM + j] / (float)cn : 0.f;
        me[gg][j] = ce > 0 ? edge_hsum[g * HDIM + j] / (float)ce : 0.f;
    }
    __syncthreads();

    float t[8];
#pragma unroll
    for (int gg = 0; gg < 8; ++gg)
        t[gg] = (cf[gg] > 0 ? bn2[j] : 0.f) + (ef[gg] > 0 ? be2[j] : 0.f);

    for (int k = 0; k < HDIM; ++k) {
        float wn = Wn2[k * HDIM + j];
#pragma unroll
        for (int gg = 0; gg < 8; ++gg) t[gg] += mn[gg][k] * wn;
    }
    for (int k = 0; k < HDIM; ++k) {
        float we = We2[k * HDIM + j];
#pragma unroll
        for (int gg = 0; gg < 8; ++gg) t[gg] += me[gg][k] * we;
    }
#pragma unroll
    for (int gg = 0; gg < 8; ++gg) tt[gg][j] = t[gg];
    __syncthreads();

    float o[8];
#pragma unroll
    for (int gg = 0; gg < 8; ++gg) o[gg] = bc[j];
    for (int k = 0; k < HDIM; ++k) {
        float wc = Wc[k * HDIM + j];
#pragma unroll
        for (int gg = 0; gg < 8; ++gg) o[gg] += tt[gg][k] * wc;
    }
#pragma unroll
    for (int gg = 0; gg < 8; ++gg)
        out[(blockIdx.x * 8 + gg) * HDIM + j] = o[gg];
}

// ---------------- launcher ----------------

extern "C" void kernel_launch(void* const* d_in, const int* in_sizes, int n_in,
                              void* d_out, int out_size, void* d_ws, size_t ws_size,
                              hipStream_t stream)
{
    const float* x         = (const float*)d_in[0];
    const float* edge_attr = (const float*)d_in[1];
    const int*   batch_idx = (const int*)d_in[2];
    const int*   edge_src  = (const int*)d_in[3];
    const float* Wn1 = (const float*)d_in[4];
    const float* bn1 = (const float*)d_in[5];
    const float* Wn2 = (const float*)d_in[6];
    const float* bn2 = (const float*)d_in[7];
    const float* We1 = (const float*)d_in[8];
    const float* be1 = (const float*)d_in[9];
    const float* We2 = (const float*)d_in[10];
    const float* be2 = (const float*)d_in[11];
    const float* Wc  = (const float*)d_in[12];
    const float* bc  = (const float*)d_in[13];
    float* out = (float*)d_out;

    // workspace layout
    float* node_hsum  = (float*)d_ws;                    // 512*256
    float* edge_hsum  = node_hsum + NG * HDIM;           // 512*256
    int*   node_cnt   = (int*)(edge_hsum + NG * HDIM);   // 512
    int*   edge_cnt   = node_cnt + NG;                   // 512
    int*   edge_base  = edge_cnt + NG;                   // 512
    int*   edge_cursor= edge_base + NG;                  // 512
    int*   edge_batch = edge_cursor + NG;                // 1e6
    int*   sorted_edge= edge_batch + N_EDGES;            // 1e6
    int*   sorted_seg = sorted_edge + N_EDGES;           // 1e6

    const size_t zbytes = (size_t)2 * NG * HDIM * sizeof(float) + 2 * NG * sizeof(int);
    hipMemsetAsync(d_ws, 0, zbytes, stream);

    node_hist_kernel<<<dim3(256), dim3(256), 0, stream>>>(batch_idx, node_cnt);
    edge_hist_kernel<<<dim3(1024), dim3(256), 0, stream>>>(edge_src, batch_idx, edge_batch, edge_cnt);
    scan_kernel<<<dim3(1), dim3(512), 0, stream>>>(edge_cnt, edge_base, edge_cursor);
    scatter_kernel<<<dim3(1024), dim3(256), 0, stream>>>(edge_batch, edge_cursor, sorted_edge, sorted_seg);

    gemm_seg_kernel<D_NODE, false><<<dim3(2048), dim3(256), 0, stream>>>(
        x, Wn1, bn1, nullptr, batch_idx, node_hsum, N_NODES / 64);
    gemm_seg_kernel<D_EDGE, true><<<dim3(2048), dim3(256), 0, stream>>>(
        edge_attr, We1, be1, sorted_edge, sorted_seg, edge_hsum, N_EDGES / 64);

    final_kernel<<<dim3(NG / 8), dim3(256), 0, stream>>>(
        node_hsum, edge_hsum, node_cnt, edge_cnt, Wn2, bn2, We2, be2, Wc, bc, out);
}

// Round 2
// 746.843 us; speedup vs baseline: 1.3043x; 1.3043x over previous
//
#include <hip/hip_runtime.h>

#define N_NODES 200000
#define N_EDGES 1000000
#define NG      512
#define D_NODE  128
#define D_EDGE  64
#define HDIM    256

typedef __attribute__((ext_vector_type(8))) short  short8;   // 8 bf16 in 4 VGPRs
typedef __attribute__((ext_vector_type(4))) float  f32x4;

__device__ __forceinline__ unsigned short f2bf(float f) {
    unsigned u = __float_as_uint(f);
    u += 0x7FFFu + ((u >> 16) & 1u);      // RNE
    return (unsigned short)(u >> 16);
}
__device__ __forceinline__ unsigned pack2(float a, float b) {
    return (unsigned)f2bf(a) | ((unsigned)f2bf(b) << 16);
}

// ---------------- histogram / sort kernels ----------------

__global__ __launch_bounds__(256) void node_hist_kernel(
    const int* __restrict__ batch_idx, int* __restrict__ node_cnt)
{
    __shared__ int h[NG];
    for (int i = threadIdx.x; i < NG; i += 256) h[i] = 0;
    __syncthreads();
    for (int n = blockIdx.x * 256 + threadIdx.x; n < N_NODES; n += gridDim.x * 256)
        atomicAdd(&h[batch_idx[n]], 1);
    __syncthreads();
    for (int i = threadIdx.x; i < NG; i += 256)
        if (h[i]) atomicAdd(&node_cnt[i], h[i]);
}

__global__ __launch_bounds__(256) void edge_hist_kernel(
    const int* __restrict__ edge_src, const int* __restrict__ batch_idx,
    int* __restrict__ edge_batch, int* __restrict__ edge_cnt)
{
    __shared__ int h[NG];
    for (int i = threadIdx.x; i < NG; i += 256) h[i] = 0;
    __syncthreads();
    for (int e = blockIdx.x * 256 + threadIdx.x; e < N_EDGES; e += gridDim.x * 256) {
        int g = batch_idx[edge_src[e]];
        edge_batch[e] = g;
        atomicAdd(&h[g], 1);
    }
    __syncthreads();
    for (int i = threadIdx.x; i < NG; i += 256)
        if (h[i]) atomicAdd(&edge_cnt[i], h[i]);
}

__global__ __launch_bounds__(512) void scan_kernel(
    const int* __restrict__ edge_cnt, int* __restrict__ edge_base,
    int* __restrict__ edge_cursor)
{
    __shared__ int tmp[NG];
    int i = threadIdx.x;               // 512 threads
    int v = edge_cnt[i];
    tmp[i] = v;
    __syncthreads();
    int sum = v;
    for (int off = 1; off < NG; off <<= 1) {
        int add = (i >= off) ? tmp[i - off] : 0;
        __syncthreads();
        sum += add;
        tmp[i] = sum;
        __syncthreads();
    }
    int excl = sum - v;
    edge_base[i]   = excl;
    edge_cursor[i] = excl;
}

// Block-aggregated counting-sort scatter: per-block LDS histogram, ONE global
// atomic per (block, graph) to reserve a range, LDS-atomic local ranks.
#define SCAT_EPB 4096
__global__ __launch_bounds__(256) void scatter_kernel(
    const int* __restrict__ edge_batch, int* __restrict__ edge_cursor,
    int* __restrict__ sorted_edge, int* __restrict__ sorted_seg)
{
    __shared__ int h[NG];
    __shared__ int base[NG];
    const int b0 = blockIdx.x * SCAT_EPB;
    const int nE = min(SCAT_EPB, N_EDGES - b0);

    for (int i = threadIdx.x; i < NG; i += 256) h[i] = 0;
    __syncthreads();
    for (int i = threadIdx.x; i < nE; i += 256)
        atomicAdd(&h[edge_batch[b0 + i]], 1);
    __syncthreads();
    for (int g = threadIdx.x; g < NG; g += 256) {
        int c = h[g];
        base[g] = c ? atomicAdd(&edge_cursor[g], c) : 0;
        h[g] = 0;
    }
    __syncthreads();
    for (int i = threadIdx.x; i < nE; i += 256) {
        int e = b0 + i;
        int g = edge_batch[e];
        int r = atomicAdd(&h[g], 1);   // LDS atomic: local rank
        int p = base[g] + r;
        sorted_edge[p] = e;
        sorted_seg[p]  = g;
    }
}

// ---------------- fused GEMM1 + relu + segment-sum ----------------
// Tile: 64 rows x 256 cols, 4 waves (one per 64-col group), 16x16x32 bf16 MFMA.
// Blocks own CONTIGUOUS tile chunks; since rows are sorted by graph id, a
// register run-accumulator (g_cur, racc[4]) carries the partial segment sum
// across tiles and flushes to global hsum with atomics only on graph change.

template<int K, bool GATHER>
__global__ __launch_bounds__(256, 2) void gemm_seg_kernel(
    const float* __restrict__ X,      // rows of length K (f32)
    const float* __restrict__ W,      // [K][256] f32
    const float* __restrict__ bias,   // [256]
    const int*  __restrict__ rowidx,  // GATHER: sorted row indices, else unused
    const int*  __restrict__ segids,  // per (sorted) row: graph id
    float* __restrict__ hsum,         // [512][256] f32, atomically accumulated
    int ntiles, int chunk)
{
    constexpr int ROWB = K * 2;       // LDS bytes per row (bf16)
    constexpr int KS   = K / 32;      // MFMA k-steps
    __shared__ __align__(16) char smem[64 * ROWB];
    __shared__ int seg_lds[64];
    __shared__ int row_lds[GATHER ? 64 : 1];

    const int tid  = threadIdx.x;
    const int lane = tid & 63;
    const int wv   = tid >> 6;        // wave 0..3 -> col group
    const int hi   = lane >> 4;       // 0..3
    const int lo   = lane & 15;
    const int colbase = wv * 64;

    // --- B fragments in registers (whole W column-slab for this wave) ---
    short8 bfrag[4][KS];
#pragma unroll
    for (int ct = 0; ct < 4; ++ct) {
        const int col = colbase + ct * 16 + lo;
#pragma unroll
        for (int ks = 0; ks < KS; ++ks) {
            short8 f;
#pragma unroll
            for (int j = 0; j < 8; ++j) {
                int k = ks * 32 + hi * 8 + j;
                f[j] = (short)f2bf(W[k * HDIM + col]);
            }
            bfrag[ct][ks] = f;
        }
    }
    float biasv[4];
#pragma unroll
    for (int ct = 0; ct < 4; ++ct) biasv[ct] = bias[colbase + ct * 16 + lo];

    const int t0 = blockIdx.x * chunk;
    const int t1 = min(t0 + chunk, ntiles);

    int   g_cur = -1;
    float racc[4] = {0.f, 0.f, 0.f, 0.f};

    for (int tile = t0; tile < t1; ++tile) {
        // stage ids
        if (tid < 64) {
            int r = tile * 64 + tid;
            seg_lds[tid] = segids[r];
            if (GATHER) row_lds[tid] = rowidx[r];
        }
        __syncthreads();

        // stage X tile -> LDS (bf16, XOR-swizzled 16B chunks)
        constexpr int F4_PER_ROW = K / 4;
        constexpr int NJ = (64 * F4_PER_ROW) / 256;
#pragma unroll
        for (int j = 0; j < NJ; ++j) {
            int f4  = tid + j * 256;
            int row = f4 / F4_PER_ROW;
            int c4  = f4 % F4_PER_ROW;
            float4 v;
            if (GATHER) {
                size_t sr = (size_t)row_lds[row];
                v = *(const float4*)(X + sr * K + c4 * 4);
            } else {
                v = *(const float4*)(X + (size_t)tile * 64 * K + (size_t)f4 * 4);
            }
            int2 p;
            p.x = (int)pack2(v.x, v.y);
            p.y = (int)pack2(v.z, v.w);
            int dst = row * ROWB + ((c4 * 8) ^ ((row & 7) << 4));
            *(int2*)(smem + dst) = p;
        }
        __syncthreads();

        // MFMA: acc[rt][ct] = X[rt*16.., :] @ W[:, ct*16..]
        f32x4 acc[4][4];
#pragma unroll
        for (int rt = 0; rt < 4; ++rt)
#pragma unroll
            for (int ct = 0; ct < 4; ++ct) acc[rt][ct] = f32x4{0.f, 0.f, 0.f, 0.f};

#pragma unroll
        for (int ks = 0; ks < KS; ++ks) {
            short8 a[4];
#pragma unroll
            for (int rt = 0; rt < 4; ++rt) {
                int row  = rt * 16 + lo;
                int koff = ks * 64 + hi * 16;
                a[rt] = *(const short8*)(smem + row * ROWB + (koff ^ ((row & 7) << 4)));
            }
#pragma unroll
            for (int rt = 0; rt < 4; ++rt)
#pragma unroll
                for (int ct = 0; ct < 4; ++ct)
                    acc[rt][ct] = __builtin_amdgcn_mfma_f32_16x16x32_bf16(
                        a[rt], bfrag[ct][ks], acc[rt][ct], 0, 0, 0);
        }

        // bias + relu in-place
#pragma unroll
        for (int rt = 0; rt < 4; ++rt)
#pragma unroll
            for (int ct = 0; ct < 4; ++ct)
#pragma unroll
                for (int r = 0; r < 4; ++r) {
                    float v = acc[rt][ct][r] + biasv[ct];
                    acc[rt][ct][r] = v > 0.f ? v : 0.f;
                }

        // segment accumulate over contiguous runs of equal graph id;
        // carry (g_cur, racc) across tiles, flush on graph transition only.
        int start = 0;
        while (start < 64) {
            int g   = seg_lds[start];
            int end = start + 1;
            while (end < 64 && seg_lds[end] == g) ++end;
            float s[4];
#pragma unroll
            for (int ct = 0; ct < 4; ++ct) {
                float v = 0.f;
#pragma unroll
                for (int rt = 0; rt < 4; ++rt) {
                    int rbase = rt * 16 + hi * 4;
#pragma unroll
                    for (int r = 0; r < 4; ++r) {
                        int row = rbase + r;
                        if (row >= start && row < end) v += acc[rt][ct][r];
                    }
                }
                v += __shfl_xor(v, 16);
                v += __shfl_xor(v, 32);
                s[ct] = v;
            }
            if (g != g_cur) {
                if (g_cur >= 0 && lane < 16) {
#pragma unroll
                    for (int ct = 0; ct < 4; ++ct)
                        atomicAdd(&hsum[g_cur * HDIM + colbase + ct * 16 + lane], racc[ct]);
                }
                g_cur = g;
#pragma unroll
                for (int ct = 0; ct < 4; ++ct) racc[ct] = s[ct];
            } else {
#pragma unroll
                for (int ct = 0; ct < 4; ++ct) racc[ct] += s[ct];
            }
            start = end;
        }
        __syncthreads();   // protect smem/seg_lds before next tile
    }

    // final flush
    if (g_cur >= 0 && lane < 16) {
#pragma unroll
        for (int ct = 0; ct < 4; ++ct)
            atomicAdd(&hsum[g_cur * HDIM + colbase + ct * 16 + lane], racc[ct]);
    }
}

// ---------------- finisher: means, 2nd linears, combine ----------------

__global__ __launch_bounds__(256) void final_kernel(
    const float* __restrict__ node_hsum, const float* __restrict__ edge_hsum,
    const int* __restrict__ node_cnt, const int* __restrict__ edge_cnt,
    const float* __restrict__ Wn2, const float* __restrict__ bn2,
    const float* __restrict__ We2, const float* __restrict__ be2,
    const float* __restrict__ Wc,  const float* __restrict__ bc,
    float* __restrict__ out)
{
    __shared__ float mn[8][HDIM], me[8][HDIM], tt[8][HDIM];
    __shared__ int cf[8], ef[8];
    const int j = threadIdx.x;

#pragma unroll
    for (int gg = 0; gg < 8; ++gg) {
        int g = blockIdx.x * 8 + gg;
        int cn = node_cnt[g], ce = edge_cnt[g];
        if (j == 0) { cf[gg] = cn; ef[gg] = ce; }
        mn[gg][j] = cn > 0 ? node_hsum[g * HDIM + j] / (float)cn : 0.f;
        me[gg][j] = ce > 0 ? edge_hsum[g * HDIM + j] / (float)ce : 0.f;
    }
    __syncthreads();

    float t[8];
#pragma unroll
    for (int gg = 0; gg < 8; ++gg)
        t[gg] = (cf[gg] > 0 ? bn2[j] : 0.f) + (ef[gg] > 0 ? be2[j] : 0.f);

    for (int k = 0; k < HDIM; ++k) {
        float wn = Wn2[k * HDIM + j];
#pragma unroll
        for (int gg = 0; gg < 8; ++gg) t[gg] += mn[gg][k] * wn;
    }
    for (int k = 0; k < HDIM; ++k) {
        float we = We2[k * HDIM + j];
#pragma unroll
        for (int gg = 0; gg < 8; ++gg) t[gg] += me[gg][k] * we;
    }
#pragma unroll
    for (int gg = 0; gg < 8; ++gg) tt[gg][j] = t[gg];
    __syncthreads();

    float o[8];
#pragma unroll
    for (int gg = 0; gg < 8; ++gg) o[gg] = bc[j];
    for (int k = 0; k < HDIM; ++k) {
        float wc = Wc[k * HDIM + j];
#pragma unroll
        for (int gg = 0; gg < 8; ++gg) o[gg] += tt[gg][k] * wc;
    }
#pragma unroll
    for (int gg = 0; gg < 8; ++gg)
        out[(blockIdx.x * 8 + gg) * HDIM + j] = o[gg];
}

// ---------------- launcher ----------------

extern "C" void kernel_launch(void* const* d_in, const int* in_sizes, int n_in,
                              void* d_out, int out_size, void* d_ws, size_t ws_size,
                              hipStream_t stream)
{
    const float* x         = (const float*)d_in[0];
    const float* edge_attr = (const float*)d_in[1];
    const int*   batch_idx = (const int*)d_in[2];
    const int*   edge_src  = (const int*)d_in[3];
    const float* Wn1 = (const float*)d_in[4];
    const float* bn1 = (const float*)d_in[5];
    const float* Wn2 = (const float*)d_in[6];
    const float* bn2 = (const float*)d_in[7];
    const float* We1 = (const float*)d_in[8];
    const float* be1 = (const float*)d_in[9];
    const float* We2 = (const float*)d_in[10];
    const float* be2 = (const float*)d_in[11];
    const float* Wc  = (const float*)d_in[12];
    const float* bc  = (const float*)d_in[13];
    float* out = (float*)d_out;

    // workspace layout
    float* node_hsum  = (float*)d_ws;                    // 512*256
    float* edge_hsum  = node_hsum + NG * HDIM;           // 512*256
    int*   node_cnt   = (int*)(edge_hsum + NG * HDIM);   // 512
    int*   edge_cnt   = node_cnt + NG;                   // 512
    int*   edge_base  = edge_cnt + NG;                   // 512
    int*   edge_cursor= edge_base + NG;                  // 512
    int*   edge_batch = edge_cursor + NG;                // 1e6
    int*   sorted_edge= edge_batch + N_EDGES;            // 1e6
    int*   sorted_seg = sorted_edge + N_EDGES;           // 1e6

    const size_t zbytes = (size_t)2 * NG * HDIM * sizeof(float) + 2 * NG * sizeof(int);
    hipMemsetAsync(d_ws, 0, zbytes, stream);

    node_hist_kernel<<<dim3(256), dim3(256), 0, stream>>>(batch_idx, node_cnt);
    edge_hist_kernel<<<dim3(1024), dim3(256), 0, stream>>>(edge_src, batch_idx, edge_batch, edge_cnt);
    scan_kernel<<<dim3(1), dim3(512), 0, stream>>>(edge_cnt, edge_base, edge_cursor);

    const int scat_blocks = (N_EDGES + SCAT_EPB - 1) / SCAT_EPB;   // 245
    scatter_kernel<<<dim3(scat_blocks), dim3(256), 0, stream>>>(
        edge_batch, edge_cursor, sorted_edge, sorted_seg);

    // node: 3125 tiles, chunk 4 -> 782 blocks (chunk ~256 nodes ~ 0.7 graphs)
    {
        const int ntiles = N_NODES / 64, chunk = 4;
        const int blocks = (ntiles + chunk - 1) / chunk;
        gemm_seg_kernel<D_NODE, false><<<dim3(blocks), dim3(256), 0, stream>>>(
            x, Wn1, bn1, nullptr, batch_idx, node_hsum, ntiles, chunk);
    }
    // edge: 15625 tiles, chunk 16 -> 977 blocks (chunk ~1024 edges ~ 0.5 graphs)
    {
        const int ntiles = N_EDGES / 64, chunk = 16;
        const int blocks = (ntiles + chunk - 1) / chunk;
        gemm_seg_kernel<D_EDGE, true><<<dim3(blocks), dim3(256), 0, stream>>>(
            edge_attr, We1, be1, sorted_edge, sorted_seg, edge_hsum, ntiles, chunk);
    }

    final_kernel<<<dim3(NG / 8), dim3(256), 0, stream>>>(
        node_hsum, edge_hsum, node_cnt, edge_cnt, Wn2, bn2, We2, be2, Wc, bc, out);
}